// Round 1
// baseline (619.671 us; speedup 1.0000x reference)
//
#include <hip/hip_runtime.h>
#include <math.h>

#define B_ROWS 4096
#define C_COLS 16000
#define NTH 10
static_assert((B_ROWS & (B_ROWS - 1)) == 0, "B pow2");

__device__ __forceinline__ void block_sum2(float& a, float& b) {
#pragma unroll
  for (int off = 32; off > 0; off >>= 1) {
    a += __shfl_down(a, off);
    b += __shfl_down(b, off);
  }
  __shared__ float sa[4], sb[4];
  const int w = threadIdx.x >> 6;
  if ((threadIdx.x & 63) == 0) { sa[w] = a; sb[w] = b; }
  __syncthreads();
  if (threadIdx.x == 0) {
    a = sa[0] + sa[1] + sa[2] + sa[3];
    b = sb[0] + sb[1] + sb[2] + sb[3];
  }
}

// ---------------- K1: per-row pass over z_s and z_t ----------------
// Per row: argmax index, sum of exp(z), and for i in [0,10): count of
// elements strictly below z[row][i]  (== ascending-argsort position p_i).
__global__ __launch_bounds__(256) void k_rowpass(
    const float* __restrict__ zs, const float* __restrict__ zt,
    float* __restrict__ rinv, int* __restrict__ jmax, int* __restrict__ pos)
{
  const int bid = blockIdx.x;
  const int m = bid >> 12;            // 0 = student, 1 = teacher
  const int r = bid & (B_ROWS - 1);
  const float* __restrict__ z = (m ? zt : zs) + (size_t)r * C_COLS;

  float th[NTH];
#pragma unroll
  for (int i = 0; i < NTH; ++i) th[i] = z[i];

  int cnt[NTH];
#pragma unroll
  for (int i = 0; i < NTH; ++i) cnt[i] = 0;

  float vmax = -__builtin_inff();
  int vidx = 0;
  float sume = 0.f;

  const float4* __restrict__ z4 = (const float4*)z;   // C_COLS % 4 == 0
  for (int it = threadIdx.x; it < C_COLS / 4; it += 256) {
    const float4 v = z4[it];
    const int c = it * 4;
    const float xs[4] = {v.x, v.y, v.z, v.w};
#pragma unroll
    for (int u = 0; u < 4; ++u) {
      const float x = xs[u];
#pragma unroll
      for (int i = 0; i < NTH; ++i) cnt[i] += (x < th[i]) ? 1 : 0;
      if (x > vmax) { vmax = x; vidx = c + u; }   // strict > keeps first max
      sume += __expf(x);
    }
  }

  // wave64 reduce
#pragma unroll
  for (int off = 32; off > 0; off >>= 1) {
    sume += __shfl_down(sume, off);
#pragma unroll
    for (int i = 0; i < NTH; ++i) cnt[i] += __shfl_down(cnt[i], off);
    const float ov = __shfl_down(vmax, off);
    const int oi = __shfl_down(vidx, off);
    if (ov > vmax || (ov == vmax && oi < vidx)) { vmax = ov; vidx = oi; }
  }
  __shared__ float s_sum[4], s_max[4];
  __shared__ int s_idx[4], s_cnt[4][NTH];
  const int wave = threadIdx.x >> 6;
  if ((threadIdx.x & 63) == 0) {
    s_sum[wave] = sume; s_max[wave] = vmax; s_idx[wave] = vidx;
#pragma unroll
    for (int i = 0; i < NTH; ++i) s_cnt[wave][i] = cnt[i];
  }
  __syncthreads();
  if (threadIdx.x == 0) {
    float ts = 0.f, tm = s_max[0];
    int ti = s_idx[0];
    int tc[NTH];
#pragma unroll
    for (int i = 0; i < NTH; ++i) tc[i] = 0;
    for (int w = 0; w < 4; ++w) {
      ts += s_sum[w];
      if (s_max[w] > tm || (s_max[w] == tm && s_idx[w] < ti)) { tm = s_max[w]; ti = s_idx[w]; }
#pragma unroll
      for (int i = 0; i < NTH; ++i) tc[i] += s_cnt[w][i];
    }
    const int base = m * B_ROWS + r;
    rinv[base] = 1.f / ts;
    jmax[base] = ti;
#pragma unroll
    for (int i = 0; i < NTH; ++i) {
      int p = tc[i];
      // stable argsort tie-break among the 10 threshold elements themselves
      for (int k = 0; k < i; ++k) p += (th[k] == th[i]) ? 1 : 0;
      pos[base * NTH + i] = p;
    }
  }
}

// ---------------- K2: inter-class (sparse closed-form pearson) ----------------
__global__ __launch_bounds__(256) void k_inter(
    const int* __restrict__ jmax, const int* __restrict__ pos,
    float* __restrict__ acc)
{
  const int r = blockIdx.x * 256 + threadIdx.x;
  float pear = 0.f, eq = 0.f;
  if (r < B_ROWS) {
    const int js = jmax[r];
    const int jt = jmax[B_ROWS + r];
    eq = (js == jt) ? 1.f : 0.f;
    int qs[NTH], qt[NTH];
    float vs[NTH], vt[NTH];
    int ns = 0, nt = 0;
    float sds = 0.f, sds2 = 0.f, sdt = 0.f, sdt2 = 0.f;
#pragma unroll
    for (int i = 0; i < NTH; ++i) {
      const float v = (float)(i - NTH);   // delta vs baseline rank 10
      const int p = pos[r * NTH + i];
      if (p != js) {                       // entry at position js is deleted
        qs[ns] = p - (p > js ? 1 : 0);
        vs[ns] = v; ++ns;
        sds += v; sds2 += v * v;
      }
      const int p2 = pos[(B_ROWS + r) * NTH + i];
      if (p2 != jt) {
        qt[nt] = p2 - (p2 > jt ? 1 : 0);
        vt[nt] = v; ++nt;
        sdt += v; sdt2 += v * v;
      }
    }
    float sprod = 0.f;
    for (int a = 0; a < ns; ++a)
      for (int b = 0; b < nt; ++b)
        if (qs[a] == qt[b]) sprod += vs[a] * vt[b];
    const float Cm1 = (float)(C_COLS - 1);
    const float num  = sprod - sds * sdt / Cm1;
    const float vars = sds2 - sds * sds / Cm1;
    const float vart = sdt2 - sdt * sdt / Cm1;
    pear = num / (sqrtf(fmaxf(vars, 0.f)) * sqrtf(fmaxf(vart, 0.f)) + 1e-8f);
  }
  block_sum2(pear, eq);
  if (threadIdx.x == 0) {
    atomicAdd(&acc[0], pear);
    atomicAdd(&acc[1], eq);
  }
}

// ---------------- K3: per-column softmax moments ----------------
__global__ __launch_bounds__(256) void k_colpass(
    const float* __restrict__ zs, const float* __restrict__ zt,
    const float* __restrict__ rinv, float* __restrict__ colacc)
{
  const int c = blockIdx.x * 256 + threadIdx.x;
  const int r0 = blockIdx.y * 64;
  if (c >= C_COLS) return;
  float s1 = 0.f, s2 = 0.f, t1 = 0.f, t2 = 0.f, st = 0.f;
  size_t off = (size_t)r0 * C_COLS + (size_t)c;
#pragma unroll 4
  for (int k = 0; k < 64; ++k) {
    const float a = __expf(zs[off]) * rinv[r0 + k];
    const float b = __expf(zt[off]) * rinv[B_ROWS + r0 + k];
    s1 += a; s2 += a * a;
    t1 += b; t2 += b * b;
    st += a * b;
    off += C_COLS;
  }
  atomicAdd(&colacc[0 * C_COLS + c], s1);
  atomicAdd(&colacc[1 * C_COLS + c], t1);
  atomicAdd(&colacc[2 * C_COLS + c], s2);
  atomicAdd(&colacc[3 * C_COLS + c], t2);
  atomicAdd(&colacc[4 * C_COLS + c], st);
}

// ---------------- K4: per-column pearson + reduce ----------------
__global__ __launch_bounds__(256) void k_intra(
    const float* __restrict__ colacc, float* __restrict__ acc)
{
  const int c = blockIdx.x * 256 + threadIdx.x;
  float pear = 0.f, dummy = 0.f;
  if (c < C_COLS) {
    const float s1 = colacc[0 * C_COLS + c];
    const float t1 = colacc[1 * C_COLS + c];
    const float s2 = colacc[2 * C_COLS + c];
    const float t2 = colacc[3 * C_COLS + c];
    const float st = colacc[4 * C_COLS + c];
    const float Bf = (float)B_ROWS;
    const float num = st - s1 * t1 / Bf;
    const float vs = fmaxf(s2 - s1 * s1 / Bf, 0.f);
    const float vt = fmaxf(t2 - t1 * t1 / Bf, 0.f);
    pear = num / (sqrtf(vs) * sqrtf(vt) + 1e-8f);
  }
  block_sum2(pear, dummy);
  if (threadIdx.x == 0) atomicAdd(&acc[2], pear);
}

// ---------------- K5: final scalar ----------------
__global__ void k_final(const float* __restrict__ acc, float* __restrict__ out)
{
  if (threadIdx.x == 0) {
    const float spearman = acc[0] / (float)B_ROWS;
    const float eq = acc[1] / (float)B_ROWS;
    const float inter = 1.f - (eq + spearman);   // TAU^2 = 1
    const float intra = 1.f - acc[2] / (float)C_COLS;
    out[0] = inter + intra;                      // BETA = GAMMA = 1
  }
}

extern "C" void kernel_launch(void* const* d_in, const int* in_sizes, int n_in,
                              void* d_out, int out_size, void* d_ws, size_t ws_size,
                              hipStream_t stream) {
  const float* zs = (const float*)d_in[0];
  const float* zt = (const float*)d_in[1];
  float* out = (float*)d_out;
  float* ws = (float*)d_ws;

  // workspace layout (floats):
  float* rinv   = ws;                         // 2*B = 8192
  int*   jmax   = (int*)(ws + 8192);          // 2*B = 8192
  int*   pos    = (int*)(ws + 16384);         // 2*B*10 = 81920
  float* colacc = ws + 16384 + 81920;         // 5*C = 80000
  float* acc    = colacc + 5 * C_COLS;        // 4 scalars
  // total: 178308 floats ~= 713 KB

  hipMemsetAsync(colacc, 0, (5 * C_COLS + 4) * sizeof(float), stream);

  k_rowpass<<<2 * B_ROWS, 256, 0, stream>>>(zs, zt, rinv, jmax, pos);
  k_inter<<<B_ROWS / 256, 256, 0, stream>>>(jmax, pos, acc);
  dim3 g3((C_COLS + 255) / 256, B_ROWS / 64);
  k_colpass<<<g3, 256, 0, stream>>>(zs, zt, rinv, colacc);
  k_intra<<<(C_COLS + 255) / 256, 256, 0, stream>>>(colacc, acc);
  k_final<<<1, 64, 0, stream>>>(acc, out);
}